// Round 8
// baseline (6515.584 us; speedup 1.0000x reference)
//
#include <hip/hip_runtime.h>
#include <cstdint>
#include <cstddef>

// LSTM B=128 T=512 I=H=1024. fp32 in/out, bf16 MFMA internally.
// Recurrence: 8 groups (16 batch rows) x 32 blocks (128 packed gate-cols,
// W_h slice resident in regs), grid 256 = 1 block/CU, 1024 thr.
// Sync: direct data polling at the coherence point. Producers publish h via
// agent-scope 8B atomic exchanges (land at LLC). R8: sparse-RMW poll — one
// owner thread per 64B line RMW-polls granule 0 only (detection == data),
// then plain-ALs the rest of the line; per-granule RMW fallback for holes.
// Sentinel 0xFFFF (bf16 NaN) never occurs as real h (|h|<1 finite).
// R8 gemm: per-t 128-row tiles so x[t] (512KB) is L2-shared by all 32
// col-blocks -> x read once from HBM (was 16x).

#define B_  128
#define T_  512
#define I_  1024
#define H_  1024
#define G4_ 4096
#define SLOTG 32768ull   // u64 granules per h slot (128*1024*2B / 8)

typedef __attribute__((ext_vector_type(8))) short short8;   // 8 bf16
typedef __attribute__((ext_vector_type(4))) float f32x4;
typedef __attribute__((ext_vector_type(2))) unsigned long long u64x2;
typedef unsigned long long u64;

static __device__ __forceinline__ unsigned short f2bf(float f) {
    unsigned u = __builtin_bit_cast(unsigned, f);
    u += 0x7fffu + ((u >> 16) & 1u);          // RNE (finite inputs)
    return (unsigned short)(u >> 16);
}
static __device__ __forceinline__ float bf2f(unsigned short s) {
    unsigned u = (unsigned)s << 16;
    return __builtin_bit_cast(float, u);
}
static __device__ __forceinline__ float sigm(float x) {
    return 1.0f / (1.0f + exp2f(-1.4426950408889634f * x));
}
static __device__ __forceinline__ float tanh_(float x) {
    float e = exp2f(2.8853900817779268f * x);  // exp(2x)
    return 1.0f - 2.0f / (e + 1.0f);
}
static __device__ __forceinline__ f32x4 mfma16(short8 a, short8 b, f32x4 c) {
    return __builtin_amdgcn_mfma_f32_16x16x32_bf16(a, b, c, 0, 0, 0);
}
static __device__ __forceinline__ u64 ffbits(u64 v) {
    return ((~v) - 0x0001000100010001ull) & v & 0x8000800080008000ull;
}
#define AL(p)   __hip_atomic_load((p), __ATOMIC_RELAXED, __HIP_MEMORY_SCOPE_AGENT)
#define ARMW(p) __hip_atomic_fetch_add((p), 0ull, __ATOMIC_RELAXED, __HIP_MEMORY_SCOPE_AGENT)

// ---- pack all 8 weights: z 0-3 = W_x gates -> Winp, z 4-7 = W_h -> Whp ----
__global__ __launch_bounds__(256) void pack_w8(
    const float* w0, const float* w1, const float* w2, const float* w3,
    const float* w4, const float* w5, const float* w6, const float* w7,
    unsigned short* __restrict__ Winp, unsigned short* __restrict__ Whp) {
    const float* ws[8] = {w0, w1, w2, w3, w4, w5, w6, w7};
    const float* W = ws[blockIdx.z];
    unsigned short* dst = (blockIdx.z < 4) ? Winp : Whp;
    const int g = blockIdx.z & 3;
    __shared__ float tile[64][65];
    const int tid = threadIdx.x;
    const int k0 = blockIdx.y * 64;
    const int j0 = blockIdx.x * 64;
    {
        const int r  = tid >> 2;
        const int c0 = (tid & 3) * 16;
        const float* src = W + (size_t)(k0 + r) * H_ + j0 + c0;
        #pragma unroll
        for (int q = 0; q < 4; ++q) {
            float4 v = *(const float4*)(src + q * 4);
            tile[r][c0 + q*4 + 0] = v.x;
            tile[r][c0 + q*4 + 1] = v.y;
            tile[r][c0 + q*4 + 2] = v.z;
            tile[r][c0 + q*4 + 3] = v.w;
        }
    }
    __syncthreads();
    {
        const int jl   = tid >> 2;
        const int kseg = (tid & 3) * 16;
        unsigned short* orow = dst + ((size_t)(j0 + jl) * 4 + g) * 1024 + (k0 + kseg);
        #pragma unroll
        for (int q = 0; q < 16; q += 4) {
            ushort4 u;
            u.x = f2bf(tile[kseg + q + 0][jl]);
            u.y = f2bf(tile[kseg + q + 1][jl]);
            u.z = f2bf(tile[kseg + q + 2][jl]);
            u.w = f2bf(tile[kseg + q + 3][jl]);
            *(ushort4*)(orow + q) = u;
        }
    }
}

__global__ __launch_bounds__(256) void pack_bias(
    const float* b0x, const float* b0h, const float* b1x, const float* b1h,
    const float* b2x, const float* b2h, const float* b3x, const float* b3h,
    float* __restrict__ out) {
    int jc = blockIdx.x * 256 + threadIdx.x;
    int g = jc & 3, jh = jc >> 2;
    const float* bx = (g == 0) ? b0x : (g == 1) ? b1x : (g == 2) ? b2x : b3x;
    const float* bh = (g == 0) ? b0h : (g == 1) ? b1h : (g == 2) ? b2h : b3h;
    out[jc] = bx[jh] + bh[jh];
}

// ---- xp(bf16) = x(fp32, inline convert) @ Winp + bias; sentinel fill ----
// grid (32, Tcc); block = one timestep, 128 rows x 128 cols; 4 waves
// (wave w: 128 rows x 32 cols, acc[8][2]). All 32 blocks of a t share the
// same 512KB x[.,t,.] tile through L2 -> x read once from HBM.
__global__ __launch_bounds__(256) void gemm_xproj(
    const float* __restrict__ x,
    const unsigned short* __restrict__ Bt,
    const float* __restrict__ bias,
    unsigned short* __restrict__ xp,           // [Tcc][128][4096] bf16
    u64* __restrict__ sent,                    // hring slot 1 base
    int t0, int Tcc) {
    const int tid = threadIdx.x;
    const int w = tid >> 6, l = tid & 63;
    const int l15 = l & 15, hi = l >> 4;
    const int tt = blockIdx.y;                 // chunk-local timestep
    const int col0 = blockIdx.x * 128 + w * 32;
    f32x4 acc[8][2] = {};
    const float* a0 = x + ((size_t)l15 * T_ + (t0 + tt)) * I_ + hi * 8;
    const unsigned short* b0 = Bt + (size_t)(col0 + l15) * 1024 + hi * 8;
    for (int ks = 0; ks < 1024; ks += 32) {
        short8 a[8], bb[2];
        #pragma unroll
        for (int mi = 0; mi < 8; ++mi) {
            const float* ap = a0 + (size_t)mi * 16 * T_ * I_ + ks;
            float4 u = *(const float4*)ap;
            float4 v = *(const float4*)(ap + 4);
            unsigned d0 = __builtin_amdgcn_perm(__builtin_bit_cast(unsigned, u.y),
                                                __builtin_bit_cast(unsigned, u.x), 0x07060302u);
            unsigned d1 = __builtin_amdgcn_perm(__builtin_bit_cast(unsigned, u.w),
                                                __builtin_bit_cast(unsigned, u.z), 0x07060302u);
            unsigned d2 = __builtin_amdgcn_perm(__builtin_bit_cast(unsigned, v.y),
                                                __builtin_bit_cast(unsigned, v.x), 0x07060302u);
            unsigned d3 = __builtin_amdgcn_perm(__builtin_bit_cast(unsigned, v.w),
                                                __builtin_bit_cast(unsigned, v.z), 0x07060302u);
            uint4 pk = {d0, d1, d2, d3};
            a[mi] = __builtin_bit_cast(short8, pk);
        }
        bb[0] = *(const short8*)(b0 + ks);
        bb[1] = *(const short8*)(b0 + 16 * 1024 + ks);
        #pragma unroll
        for (int mi = 0; mi < 8; ++mi) {
            acc[mi][0] = mfma16(a[mi], bb[0], acc[mi][0]);
            acc[mi][1] = mfma16(a[mi], bb[1], acc[mi][1]);
        }
    }
    #pragma unroll
    for (int ni = 0; ni < 2; ++ni) {
        int colg = col0 + ni * 16 + l15;
        float bs = bias[colg];
        #pragma unroll
        for (int mi = 0; mi < 8; ++mi) {
            #pragma unroll
            for (int j = 0; j < 4; ++j) {
                int row = mi * 16 + hi * 4 + j;
                xp[((size_t)tt * 128 + row) * G4_ + colg] = f2bf(acc[mi][ni][j] + bs);
            }
        }
    }
    {   // sentinel fill of ring slots 1..Tcc: 32*Tcc blocks x 256 thr x 4
        size_t sidx = ((size_t)(blockIdx.y * 32 + blockIdx.x) * 256 + tid) * 4;
        u64* sp = sent + sidx;
        sp[0] = ~0ull; sp[1] = ~0ull; sp[2] = ~0ull; sp[3] = ~0ull;
    }
}

// ---- recurrence: grid 256 x 1024 thr. grp = bx>>5, cb = bx&31.
// wave w: cq = w&3 (32 cols), kq = w>>2 (K quarter, 8 ksteps of 32).
__global__ __launch_bounds__(1024, 4) void lstm_recur(
    const unsigned short* __restrict__ Whp,
    const unsigned short* __restrict__ xp,     // [Tcc][128][4096] bf16
    u64* __restrict__ hring,                   // Tc+1 slots; slot0 = carry
    float* __restrict__ cbuf,                  // [128][1024] fp32 in/out
    float* __restrict__ outp,                  // d_out [h|c] fp32
    int Tcc, int is_last) {
    __shared__ __align__(16) char hlds[32768];     // fragment-order h tile
    __shared__ __align__(16) float gl[4][16][132]; // per-kq partial gates

    const int t = threadIdx.x;
    const int l = t & 63, w = t >> 6;
    const int l15 = l & 15, hi = l >> 4;
    const int cq = w & 3, kq = w >> 2;
    const int grp = blockIdx.x >> 5, cb = blockIdx.x & 31;
    const int row0 = grp * 16;

    // resident W_h: 2 col-tiles x 8 ksteps = 64 regs
    short8 wf[2][8];
    {
        const unsigned short* wb = Whp + (size_t)(cb * 128 + cq * 32 + l15) * 1024
                                       + kq * 256 + hi * 8;
        #pragma unroll
        for (int ci = 0; ci < 2; ++ci)
            #pragma unroll
            for (int ks = 0; ks < 8; ++ks)
                wf[ci][ks] = *(const short8*)(wb + ci * 16 * 1024 + ks * 32);
    }

    const int urow = t >> 5, ujh = t & 31;     // update mapping (t<512)
    float creg = 0.f;
    if (t < 512) creg = cbuf[(size_t)(row0 + urow) * H_ + cb * 32 + ujh];

    // line-owner mapping (t<512): line = (prow = t&15, lq = t>>4), 64B each
    const int prow = t & 15, lq = t >> 4;

    for (int st = 0; st < Tcc; ++st) {
        // xp prefetch (independent of h) — overlaps the data poll
        ushort4 xv = {0, 0, 0, 0};
        if (t < 512)
            xv = *(const ushort4*)(xp + ((size_t)st * 128 + row0 + urow) * G4_
                                      + cb * 128 + ujh * 4);

        // sparse-RMW poll of this owner's 64B line of h_t
        u64 q[8];
        if (t < 512) {
            u64* rp = hring + (size_t)st * SLOTG + (size_t)(row0 + prow) * 256 + lq * 8;
            q[0] = ARMW(rp);
            while (ffbits(q[0])) {
                __builtin_amdgcn_s_sleep(1);
                q[0] = ARMW(rp);
            }
            q[1] = AL(rp + 1); q[2] = AL(rp + 2); q[3] = AL(rp + 3);
            q[4] = AL(rp + 4); q[5] = AL(rp + 5); q[6] = AL(rp + 6); q[7] = AL(rp + 7);
            u64 bad = ffbits(q[1]) | ffbits(q[2]) | ffbits(q[3]) | ffbits(q[4])
                    | ffbits(q[5]) | ffbits(q[6]) | ffbits(q[7]);
            while (bad) {              // rare: publish burst not fully landed
                __builtin_amdgcn_s_sleep(1);
                q[1] = ARMW(rp + 1); q[2] = ARMW(rp + 2); q[3] = ARMW(rp + 3);
                q[4] = ARMW(rp + 4); q[5] = ARMW(rp + 5); q[6] = ARMW(rp + 6);
                q[7] = ARMW(rp + 7);
                bad = ffbits(q[1]) | ffbits(q[2]) | ffbits(q[3]) | ffbits(q[4])
                    | ffbits(q[5]) | ffbits(q[6]) | ffbits(q[7]);
            }
            // stage fragment-order: ko = lq*4+j, off = (ko*16+prow)*16.
            // quarter-wave lanes have prow 0..15 at fixed (lq,j) -> 256B
            // contiguous -> conflict-free.
            #pragma unroll
            for (int j = 0; j < 4; ++j) {
                u64x2 v = {q[2 * j], q[2 * j + 1]};
                *(u64x2*)(hlds + ((lq * 4 + j) * 16 + prow) * 16) = v;
            }
        }
        __syncthreads();

        // MFMA: lane-contiguous A reads (conflict-free)
        f32x4 acc[2] = {};
        #pragma unroll
        for (int ks = 0; ks < 8; ++ks) {
            int ko = (kq * 8 + ks) * 4 + hi;
            short8 a = *(const short8*)(hlds + ko * 256 + l15 * 16);
            acc[0] = mfma16(a, wf[0][ks], acc[0]);
            acc[1] = mfma16(a, wf[1][ks], acc[1]);
        }
        #pragma unroll
        for (int ci = 0; ci < 2; ++ci)
            #pragma unroll
            for (int j = 0; j < 4; ++j)
                gl[kq][hi * 4 + j][cq * 32 + ci * 16 + l15] = acc[ci][j];
        __syncthreads();

        // update (t<512, one cell each) + packed publish via shfl
        if (t < 512) {
            float4 s = *(const float4*)&gl[0][urow][ujh * 4];
            #pragma unroll
            for (int k2 = 1; k2 < 4; ++k2) {
                float4 s2 = *(const float4*)&gl[k2][urow][ujh * 4];
                s.x += s2.x; s.y += s2.y; s.z += s2.z; s.w += s2.w;
            }
            float gi = s.x + bf2f(xv.x);
            float gf = s.y + bf2f(xv.y);
            float gg = s.z + bf2f(xv.z);
            float go = s.w + bf2f(xv.w);
            float it_ = sigm(gi), ft = sigm(gf), gt = tanh_(gg), ot = sigm(go);
            float cn = ft * creg + it_ * gt;
            float hn = ot * tanh_(cn);
            creg = cn;
            unsigned hb = (unsigned)f2bf(hn);
            unsigned ob = __shfl_xor(hb, 1);
            unsigned v01 = (l & 1) ? (ob | (hb << 16)) : (hb | (ob << 16));
            unsigned v23 = __shfl_xor(v01, 2);
            if ((t & 3) == 0) {
                u64 hw = (u64)v01 | ((u64)v23 << 32);
                int dst = (st == Tcc - 1) ? 0 : st + 1;   // carry -> slot 0
                u64* wp = hring + (size_t)dst * SLOTG
                        + (size_t)(row0 + urow) * 256 + cb * 8 + (ujh >> 2);
                (void)__hip_atomic_exchange(wp, hw, __ATOMIC_RELAXED,
                                            __HIP_MEMORY_SCOPE_AGENT);
            }
            if (is_last && st == Tcc - 1) {
                size_t o = (size_t)(row0 + urow) * H_ + cb * 32 + ujh;
                outp[o] = hn;
                outp[(size_t)B_ * H_ + o] = cn;
            }
        }
        // no extra barrier: hlds/gl reads complete before barrier-2; next
        // iteration's ds_writes come after each owner's own poll.
    }
    if (t < 512)
        cbuf[(size_t)(row0 + urow) * H_ + cb * 32 + ujh] = creg;
}

extern "C" void kernel_launch(void* const* d_in, const int* in_sizes, int n_in,
                              void* d_out, int out_size, void* d_ws, size_t ws_size,
                              hipStream_t stream) {
    const float* x = (const float*)d_in[0];
    const float* Wx[4] = {(const float*)d_in[1], (const float*)d_in[3],
                          (const float*)d_in[5], (const float*)d_in[7]};
    const float* Wh[4] = {(const float*)d_in[2], (const float*)d_in[4],
                          (const float*)d_in[6], (const float*)d_in[8]};
    const float* bx[4] = {(const float*)d_in[9],  (const float*)d_in[11],
                          (const float*)d_in[13], (const float*)d_in[15]};
    const float* bh[4] = {(const float*)d_in[10], (const float*)d_in[12],
                          (const float*)d_in[14], (const float*)d_in[16]};

    char* p = (char*)d_ws;
    auto take = [&](size_t bytes) {
        char* q = p; p += (bytes + 255) & ~(size_t)255; return q;
    };
    unsigned short* Winp = (unsigned short*)take((size_t)G4_ * 1024 * 2);
    unsigned short* Whp  = (unsigned short*)take((size_t)G4_ * 1024 * 2);
    float*          bias = (float*)take(G4_ * 4);
    float*          cbuf = (float*)take((size_t)B_ * H_ * 4);
    size_t fixed = (size_t)(p - (char*)d_ws) + SLOTG * 8 + 512;  // + ring slot 0
    size_t per = (size_t)B_ * G4_ * 2 + SLOTG * 8 + 512;         // xp + ring slot
    size_t avail = ws_size > fixed ? ws_size - fixed : 0;
    int Tc = (int)(avail / per);
    if (Tc > T_) Tc = T_;
    if (Tc < 2) Tc = 2;                       // needs ~22 MB ws minimum
    unsigned short* xpc   = (unsigned short*)take((size_t)Tc * B_ * G4_ * 2);
    u64*            hring = (u64*)take((size_t)(Tc + 1) * SLOTG * 8);

    pack_w8<<<dim3(16, 16, 8), 256, 0, stream>>>(
        Wx[0], Wx[1], Wx[2], Wx[3], Wh[0], Wh[1], Wh[2], Wh[3], Winp, Whp);
    pack_bias<<<16, 256, 0, stream>>>(bx[0], bh[0], bx[1], bh[1],
                                      bx[2], bh[2], bx[3], bh[3], bias);
    (void)hipMemsetAsync(hring, 0, SLOTG * 8, stream);   // slot 0 = h0 = zeros
    (void)hipMemsetAsync(cbuf, 0, (size_t)B_ * H_ * 4, stream);

    int t0 = 0;
    while (t0 < T_) {
        int rem = T_ - t0;
        int Tcc = (rem < Tc) ? rem : Tc;
        if (rem - Tcc == 1) Tcc -= 1;         // never leave a 1-step chunk
        int last = (t0 + Tcc >= T_) ? 1 : 0;
        gemm_xproj<<<dim3(32, Tcc), 256, 0, stream>>>(
            x, Winp, bias, xpc, hring + SLOTG, t0, Tcc);
        lstm_recur<<<256, 1024, 0, stream>>>(Whp, xpc, hring, cbuf,
                                             (float*)d_out, Tcc, last);
        t0 += Tcc;
    }
}

// Round 9
// 4557.808 us; speedup vs baseline: 1.4295x; 1.4295x over previous
//
#include <hip/hip_runtime.h>
#include <cstdint>
#include <cstddef>

// LSTM B=128 T=512 I=H=1024. fp32 in/out, bf16 MFMA internally.
// R9 recurrence sync: per-producer-block step counters. Producers publish h
// via agent-scope 8B atomic exchanges, wave-wide vmcnt(0) drain, then one
// relaxed fetch_add(+1) per update-wave (counter full = 8). Consumers:
// wave0's 32 lanes RMW-poll the 32 producer counters (32 atomics/round vs
// 512 — LLC atomic-pipe pressure was the measured bottleneck R7->R8), then
// all threads read h via relaxed agent atomic loads (plain pipelined).
// Sentinel 0xFFFF (bf16 NaN, impossible as real h) kept as safety net.
// R9 gemm: separate convert_x (fp32->bf16 stream), bf16 fragment GEMM
// (64 t-rows x 256 cols), LDS-transposed epilogue for full-line xp stores.

#define B_  128
#define T_  512
#define I_  1024
#define H_  1024
#define G4_ 4096
#define SLOTG 32768ull   // u64 granules per h slot (128*1024*2B / 8)

typedef __attribute__((ext_vector_type(8))) short short8;   // 8 bf16
typedef __attribute__((ext_vector_type(4))) float f32x4;
typedef __attribute__((ext_vector_type(2))) unsigned long long u64x2;
typedef unsigned long long u64;

static __device__ __forceinline__ unsigned short f2bf(float f) {
    unsigned u = __builtin_bit_cast(unsigned, f);
    u += 0x7fffu + ((u >> 16) & 1u);          // RNE (finite inputs)
    return (unsigned short)(u >> 16);
}
static __device__ __forceinline__ float bf2f(unsigned short s) {
    unsigned u = (unsigned)s << 16;
    return __builtin_bit_cast(float, u);
}
static __device__ __forceinline__ float sigm(float x) {
    return 1.0f / (1.0f + exp2f(-1.4426950408889634f * x));
}
static __device__ __forceinline__ float tanh_(float x) {
    float e = exp2f(2.8853900817779268f * x);  // exp(2x)
    return 1.0f - 2.0f / (e + 1.0f);
}
static __device__ __forceinline__ f32x4 mfma16(short8 a, short8 b, f32x4 c) {
    return __builtin_amdgcn_mfma_f32_16x16x32_bf16(a, b, c, 0, 0, 0);
}
static __device__ __forceinline__ u64 ffbits(u64 v) {
    return ((~v) - 0x0001000100010001ull) & v & 0x8000800080008000ull;
}
#define AL(p)    __hip_atomic_load((p), __ATOMIC_RELAXED, __HIP_MEMORY_SCOPE_AGENT)
#define ARMW(p)  __hip_atomic_fetch_add((p), 0ull, __ATOMIC_RELAXED, __HIP_MEMORY_SCOPE_AGENT)
#define ARMW32(p) __hip_atomic_fetch_add((p), 0u, __ATOMIC_RELAXED, __HIP_MEMORY_SCOPE_AGENT)

// ---- pack all 8 weights: z 0-3 = W_x gates -> Winp, z 4-7 = W_h -> Whp ----
__global__ __launch_bounds__(256) void pack_w8(
    const float* w0, const float* w1, const float* w2, const float* w3,
    const float* w4, const float* w5, const float* w6, const float* w7,
    unsigned short* __restrict__ Winp, unsigned short* __restrict__ Whp) {
    const float* ws[8] = {w0, w1, w2, w3, w4, w5, w6, w7};
    const float* W = ws[blockIdx.z];
    unsigned short* dst = (blockIdx.z < 4) ? Winp : Whp;
    const int g = blockIdx.z & 3;
    __shared__ float tile[64][65];
    const int tid = threadIdx.x;
    const int k0 = blockIdx.y * 64;
    const int j0 = blockIdx.x * 64;
    {
        const int r  = tid >> 2;
        const int c0 = (tid & 3) * 16;
        const float* src = W + (size_t)(k0 + r) * H_ + j0 + c0;
        #pragma unroll
        for (int q = 0; q < 4; ++q) {
            float4 v = *(const float4*)(src + q * 4);
            tile[r][c0 + q*4 + 0] = v.x;
            tile[r][c0 + q*4 + 1] = v.y;
            tile[r][c0 + q*4 + 2] = v.z;
            tile[r][c0 + q*4 + 3] = v.w;
        }
    }
    __syncthreads();
    {
        const int jl   = tid >> 2;
        const int kseg = (tid & 3) * 16;
        unsigned short* orow = dst + ((size_t)(j0 + jl) * 4 + g) * 1024 + (k0 + kseg);
        #pragma unroll
        for (int q = 0; q < 16; q += 4) {
            ushort4 u;
            u.x = f2bf(tile[kseg + q + 0][jl]);
            u.y = f2bf(tile[kseg + q + 1][jl]);
            u.z = f2bf(tile[kseg + q + 2][jl]);
            u.w = f2bf(tile[kseg + q + 3][jl]);
            *(ushort4*)(orow + q) = u;
        }
    }
}

__global__ __launch_bounds__(256) void pack_bias(
    const float* b0x, const float* b0h, const float* b1x, const float* b1h,
    const float* b2x, const float* b2h, const float* b3x, const float* b3h,
    float* __restrict__ out) {
    int jc = blockIdx.x * 256 + threadIdx.x;
    int g = jc & 3, jh = jc >> 2;
    const float* bx = (g == 0) ? b0x : (g == 1) ? b1x : (g == 2) ? b2x : b3x;
    const float* bh = (g == 0) ? b0h : (g == 1) ? b1h : (g == 2) ? b2h : b3h;
    out[jc] = bx[jh] + bh[jh];
}

// cnt layout: [(T_+1) steps][8 grp][32 cb] x 16 u32 (64B line each).
// step-0 counters = 8 ("h0 published"), all else 0.
__global__ __launch_bounds__(256) void init_cnt(unsigned* __restrict__ cnt, int total) {
    int i = blockIdx.x * 256 + threadIdx.x;
    if (i < total) cnt[i] = (i < 8 * 32 * 16) ? 8u : 0u;
}

// ---- x fp32 -> xb bf16, chunk-local rows r = b*Tcc+tc ----
__global__ __launch_bounds__(256) void convert_x(const float* __restrict__ x,
                                                 unsigned short* __restrict__ xb,
                                                 int t0, int Tcc) {
    int e = blockIdx.x * 256 + threadIdx.x;
    int i = (e & 127) << 3;
    int r = e >> 7;
    int b = r / Tcc, tc = r - b * Tcc;
    const float* s = x + (size_t)(b * T_ + t0 + tc) * I_ + i;
    float4 v0 = *(const float4*)s;
    float4 v1 = *(const float4*)(s + 4);
    ushort4 u0; u0.x = f2bf(v0.x); u0.y = f2bf(v0.y); u0.z = f2bf(v0.z); u0.w = f2bf(v0.w);
    ushort4 u1; u1.x = f2bf(v1.x); u1.y = f2bf(v1.y); u1.z = f2bf(v1.z); u1.w = f2bf(v1.w);
    unsigned short* d = xb + (size_t)r * I_ + i;
    *(ushort4*)d = u0;
    *(ushort4*)(d + 4) = u1;
}

// ---- xp(bf16) = xb @ Winp + bias; LDS-transposed epilogue; sentinel fill ----
// grid (16, 2*Tcc); 4 waves: 64 rows x 64 cols each (block: 64r x 256c).
__global__ __launch_bounds__(256) void gemm_xproj(
    const unsigned short* __restrict__ A,      // xb [128*Tcc][1024]
    const unsigned short* __restrict__ Bt,
    const float* __restrict__ bias,
    unsigned short* __restrict__ xp,           // [Tcc][128][4096] bf16
    u64* __restrict__ sent,                    // hring slot 1 base
    int Tcc) {
    __shared__ unsigned short ot[64][256];     // 32KB epilogue stage
    const int tid = threadIdx.x;
    const int w = tid >> 6, l = tid & 63;
    const int l15 = l & 15, hi = l >> 4;
    const int row0 = blockIdx.y * 64;
    const int col0 = blockIdx.x * 256 + w * 64;
    f32x4 acc[4][4] = {};
    const unsigned short* a0 = A  + (size_t)(row0 + l15) * 1024 + hi * 8;
    const unsigned short* b0 = Bt + (size_t)(col0 + l15) * 1024 + hi * 8;
    for (int ks = 0; ks < 1024; ks += 32) {
        short8 a[4], bb[4];
        #pragma unroll
        for (int mi = 0; mi < 4; ++mi) a[mi]  = *(const short8*)(a0 + (size_t)mi * 16 * 1024 + ks);
        #pragma unroll
        for (int ni = 0; ni < 4; ++ni) bb[ni] = *(const short8*)(b0 + (size_t)ni * 16 * 1024 + ks);
        #pragma unroll
        for (int mi = 0; mi < 4; ++mi)
            #pragma unroll
            for (int ni = 0; ni < 4; ++ni)
                acc[mi][ni] = mfma16(a[mi], bb[ni], acc[mi][ni]);
    }
    #pragma unroll
    for (int mi = 0; mi < 4; ++mi) {
        #pragma unroll
        for (int ni = 0; ni < 4; ++ni) {
            float bs = bias[col0 + ni * 16 + l15];
            #pragma unroll
            for (int j = 0; j < 4; ++j)
                ot[mi * 16 + hi * 4 + j][w * 64 + ni * 16 + l15] =
                    f2bf(acc[mi][ni][j] + bs);
        }
    }
    __syncthreads();
    {   // coalesced xp store: thread -> (row rl, 128B chunk)
        const int rl = tid >> 2, ch = tid & 3;
        int r = row0 + rl;
        int b = r / Tcc, tc = r - b * Tcc;
        unsigned short* dst = xp + (size_t)(tc * 128 + b) * G4_
                            + blockIdx.x * 256 + ch * 64;
        const unsigned short* src = &ot[rl][ch * 64];
        #pragma unroll
        for (int q = 0; q < 8; ++q)
            *(uint4*)(dst + q * 8) = *(const uint4*)(src + q * 8);
    }
    {   // sentinel fill: 32*Tcc blocks x 256 thr x 4 u64 covers Tcc slots
        size_t bid = (size_t)blockIdx.y * 16 + blockIdx.x;
        u64* sp = sent + bid * 1024 + (size_t)tid * 4;
        sp[0] = ~0ull; sp[1] = ~0ull; sp[2] = ~0ull; sp[3] = ~0ull;
    }
}

// ---- recurrence: grid 256 x 1024 thr. grp = bx>>5, cb = bx&31.
// wave w: cq = w&3 (32 cols), kq = w>>2 (K quarter, 8 ksteps of 32).
__global__ __launch_bounds__(1024, 4) void lstm_recur(
    const unsigned short* __restrict__ Whp,
    const unsigned short* __restrict__ xp,     // [Tcc][128][4096] bf16
    u64* __restrict__ hring,                   // Tc+1 slots; slot0 = carry
    unsigned* __restrict__ cnt,                // [(T_+1)][8][32] x16 u32
    float* __restrict__ cbuf,                  // [128][1024] fp32 in/out
    float* __restrict__ outp,                  // d_out [h|c] fp32
    int Tcc, int t0, int is_last) {
    __shared__ __align__(16) char hlds[32768];     // fragment-order h tile
    __shared__ __align__(16) float gl[4][16][132]; // per-kq partial gates

    const int t = threadIdx.x;
    const int l = t & 63, w = t >> 6;
    const int l15 = l & 15, hi = l >> 4;
    const int cq = w & 3, kq = w >> 2;
    const int grp = blockIdx.x >> 5, cb = blockIdx.x & 31;
    const int row0 = grp * 16;

    // resident W_h: 2 col-tiles x 8 ksteps = 64 regs
    short8 wf[2][8];
    {
        const unsigned short* wb = Whp + (size_t)(cb * 128 + cq * 32 + l15) * 1024
                                       + kq * 256 + hi * 8;
        #pragma unroll
        for (int ci = 0; ci < 2; ++ci)
            #pragma unroll
            for (int ks = 0; ks < 8; ++ks)
                wf[ci][ks] = *(const short8*)(wb + ci * 16 * 1024 + ks * 32);
    }

    const int urow = t >> 5, ujh = t & 31;     // update mapping (t<512)
    float creg = 0.f;
    if (t < 512) creg = cbuf[(size_t)(row0 + urow) * H_ + cb * 32 + ujh];

    const int arow = t & 15, ach = t >> 4;     // data-load mapping: 32B each

    for (int st = 0; st < Tcc; ++st) {
        // xp prefetch (independent of h) — overlaps the flag poll
        ushort4 xv = {0, 0, 0, 0};
        if (t < 512)
            xv = *(const ushort4*)(xp + ((size_t)st * 128 + row0 + urow) * G4_
                                      + cb * 128 + ujh * 4);

        // wave0: 32 lanes RMW-poll the 32 producer-block counters
        if (w == 0) {
            unsigned* fp = cnt + (((size_t)(t0 + st) * 8 + grp) * 32 + l) * 16;
            for (;;) {
                unsigned v = 8u;
                if (l < 32) v = ARMW32(fp);
                if (__all(v >= 8u)) break;
                __builtin_amdgcn_s_sleep(1);
            }
        }
        __syncthreads();

        // data via relaxed atomic loads (fresh post-detect); sentinel = net
        {
            u64* rp = hring + (size_t)st * SLOTG + (size_t)(row0 + arow) * 256 + ach * 4;
            u64 q0 = AL(rp), q1 = AL(rp + 1), q2 = AL(rp + 2), q3 = AL(rp + 3);
            while (ffbits(q0) | ffbits(q1) | ffbits(q2) | ffbits(q3)) {
                __builtin_amdgcn_s_sleep(1);
                q0 = ARMW(rp); q1 = ARMW(rp + 1); q2 = ARMW(rp + 2); q3 = ARMW(rp + 3);
            }
            u64x2 v0 = {q0, q1}, v1 = {q2, q3};
            *(u64x2*)(hlds + ((ach * 2    ) * 16 + arow) * 16) = v0;
            *(u64x2*)(hlds + ((ach * 2 + 1) * 16 + arow) * 16) = v1;
        }
        __syncthreads();

        // MFMA: lane-contiguous A reads (conflict-free)
        f32x4 acc[2] = {};
        #pragma unroll
        for (int ks = 0; ks < 8; ++ks) {
            int ko = (kq * 8 + ks) * 4 + hi;
            short8 a = *(const short8*)(hlds + ko * 256 + l15 * 16);
            acc[0] = mfma16(a, wf[0][ks], acc[0]);
            acc[1] = mfma16(a, wf[1][ks], acc[1]);
        }
        #pragma unroll
        for (int ci = 0; ci < 2; ++ci)
            #pragma unroll
            for (int j = 0; j < 4; ++j)
                gl[kq][hi * 4 + j][cq * 32 + ci * 16 + l15] = acc[ci][j];
        __syncthreads();

        // update (t<512, one cell each) + packed publish + counter add
        if (t < 512) {
            float4 s = *(const float4*)&gl[0][urow][ujh * 4];
            #pragma unroll
            for (int k2 = 1; k2 < 4; ++k2) {
                float4 s2 = *(const float4*)&gl[k2][urow][ujh * 4];
                s.x += s2.x; s.y += s2.y; s.z += s2.z; s.w += s2.w;
            }
            float gi = s.x + bf2f(xv.x);
            float gf = s.y + bf2f(xv.y);
            float gg = s.z + bf2f(xv.z);
            float go = s.w + bf2f(xv.w);
            float it_ = sigm(gi), ft = sigm(gf), gt = tanh_(gg), ot = sigm(go);
            float cn = ft * creg + it_ * gt;
            float hn = ot * tanh_(cn);
            creg = cn;
            unsigned hb = (unsigned)f2bf(hn);
            unsigned ob = __shfl_xor(hb, 1);
            unsigned v01 = (l & 1) ? (ob | (hb << 16)) : (hb | (ob << 16));
            unsigned v23 = __shfl_xor(v01, 2);
            if ((t & 3) == 0) {
                u64 hw = (u64)v01 | ((u64)v23 << 32);
                int dst = (st == Tcc - 1) ? 0 : st + 1;   // carry -> slot 0
                u64* wp = hring + (size_t)dst * SLOTG
                        + (size_t)(row0 + urow) * 256 + cb * 8 + (ujh >> 2);
                (void)__hip_atomic_exchange(wp, hw, __ATOMIC_RELAXED,
                                            __HIP_MEMORY_SCOPE_AGENT);
            }
            if (is_last && st == Tcc - 1) {
                size_t o = (size_t)(row0 + urow) * H_ + cb * 32 + ujh;
                outp[o] = hn;
                outp[(size_t)B_ * H_ + o] = cn;
            }
            // wave-wide drain of this wave's 16 exchanges, then one add
            asm volatile("s_waitcnt vmcnt(0)" ::: "memory");
            if ((t & 63) == 0)
                (void)__hip_atomic_fetch_add(
                    cnt + (((size_t)(t0 + st + 1) * 8 + grp) * 32 + cb) * 16,
                    1u, __ATOMIC_RELAXED, __HIP_MEMORY_SCOPE_AGENT);
        }
        // no trailing barrier: next hlds writes are after next B1;
        // next gl writes after next B2; update reads complete before those.
    }
    if (t < 512)
        cbuf[(size_t)(row0 + urow) * H_ + cb * 32 + ujh] = creg;
}

extern "C" void kernel_launch(void* const* d_in, const int* in_sizes, int n_in,
                              void* d_out, int out_size, void* d_ws, size_t ws_size,
                              hipStream_t stream) {
    const float* x = (const float*)d_in[0];
    const float* Wx[4] = {(const float*)d_in[1], (const float*)d_in[3],
                          (const float*)d_in[5], (const float*)d_in[7]};
    const float* Wh[4] = {(const float*)d_in[2], (const float*)d_in[4],
                          (const float*)d_in[6], (const float*)d_in[8]};
    const float* bx[4] = {(const float*)d_in[9],  (const float*)d_in[11],
                          (const float*)d_in[13], (const float*)d_in[15]};
    const float* bh[4] = {(const float*)d_in[10], (const float*)d_in[12],
                          (const float*)d_in[14], (const float*)d_in[16]};

    char* p = (char*)d_ws;
    auto take = [&](size_t bytes) {
        char* q = p; p += (bytes + 255) & ~(size_t)255; return q;
    };
    unsigned short* Winp = (unsigned short*)take((size_t)G4_ * 1024 * 2);
    unsigned short* Whp  = (unsigned short*)take((size_t)G4_ * 1024 * 2);
    float*          bias = (float*)take(G4_ * 4);
    float*          cbuf = (float*)take((size_t)B_ * H_ * 4);
    const int cnt_total = (T_ + 1) * 8 * 32 * 16;
    unsigned*       cnt  = (unsigned*)take((size_t)cnt_total * 4);
    size_t fixed = (size_t)(p - (char*)d_ws) + SLOTG * 8 + 512;  // + ring slot 0
    // per-timestep: xb bf16 + xp bf16 + one h ring slot
    size_t per = (size_t)B_ * I_ * 2 + (size_t)B_ * G4_ * 2 + SLOTG * 8 + 768;
    size_t avail = ws_size > fixed ? ws_size - fixed : 0;
    int Tc = (int)(avail / per);
    if (Tc > T_) Tc = T_;
    if (Tc < 2) Tc = 2;                       // needs ~34 MB ws minimum
    unsigned short* xb    = (unsigned short*)take((size_t)Tc * B_ * I_ * 2);
    unsigned short* xpc   = (unsigned short*)take((size_t)Tc * B_ * G4_ * 2);
    u64*            hring = (u64*)take((size_t)(Tc + 1) * SLOTG * 8);

    pack_w8<<<dim3(16, 16, 8), 256, 0, stream>>>(
        Wx[0], Wx[1], Wx[2], Wx[3], Wh[0], Wh[1], Wh[2], Wh[3], Winp, Whp);
    pack_bias<<<16, 256, 0, stream>>>(bx[0], bh[0], bx[1], bh[1],
                                      bx[2], bh[2], bx[3], bh[3], bias);
    init_cnt<<<(cnt_total + 255) / 256, 256, 0, stream>>>(cnt, cnt_total);
    (void)hipMemsetAsync(hring, 0, SLOTG * 8, stream);   // slot 0 = h0 = zeros
    (void)hipMemsetAsync(cbuf, 0, (size_t)B_ * H_ * 4, stream);

    int t0 = 0;
    while (t0 < T_) {
        int rem = T_ - t0;
        int Tcc = (rem < Tc) ? rem : Tc;
        if (rem - Tcc == 1) Tcc -= 1;         // never leave a 1-step chunk
        int last = (t0 + Tcc >= T_) ? 1 : 0;
        convert_x<<<Tcc * 64, 256, 0, stream>>>(x, xb, t0, Tcc);
        gemm_xproj<<<dim3(16, 2 * Tcc), 256, 0, stream>>>(
            xb, Winp, bias, xpc, hring + SLOTG, Tcc);
        lstm_recur<<<256, 1024, 0, stream>>>(Whp, xpc, hring, cnt, cbuf,
                                             (float*)d_out, Tcc, t0, last);
        t0 += Tcc;
    }
}